// Round 9
// baseline (1307.045 us; speedup 1.0000x reference)
//
#include <hip/hip_runtime.h>
#include <cstdint>
#include <cstddef>

// Problem constants (fixed by reference)
#define NN   8192
#define SS   128
#define EMBD 256
#define LL   128
#define HV   2000
#define EE   131072

typedef float  f32x4  __attribute__((ext_vector_type(4)));
typedef __bf16 bf16x8 __attribute__((ext_vector_type(8)));
typedef unsigned int   u32x4 __attribute__((ext_vector_type(4)));
typedef unsigned int   u32x2 __attribute__((ext_vector_type(2)));
typedef unsigned short u16x4 __attribute__((ext_vector_type(4)));

__device__ __forceinline__ unsigned short f2bf(float f) {
  unsigned u; __builtin_memcpy(&u, &f, 4);
  unsigned r = u + 0x7fffu + ((u >> 16) & 1u);   // RNE
  return (unsigned short)(r >> 16);
}
__device__ __forceinline__ float bfLo(unsigned w) {
  unsigned x = w << 16; float f; __builtin_memcpy(&f, &x, 4); return f;
}
__device__ __forceinline__ float bfHi(unsigned w) {
  unsigned x = w & 0xffff0000u; float f; __builtin_memcpy(&f, &x, 4); return f;
}

// ============================================================================
// prep: wT[col][e] bf16, col in [0,384):
//   col<128 -> Wq[:,col] ; col<256 -> Wk[:,col-128] ; else Wv[:,col-256]
// ============================================================================
__global__ void prep_w(const float* __restrict__ Wq, const float* __restrict__ Wk,
                       const float* __restrict__ Wv, unsigned short* __restrict__ wT) {
  int idx = blockIdx.x * 256 + threadIdx.x;      // 98304 = 384 cols x 256 e
  int c = idx >> 8, e = idx & 255;
  float v = (c < 128) ? Wq[(size_t)e * LL + c]
          : (c < 256) ? Wk[(size_t)e * LL + (c - 128)]
                      : Wv[(size_t)e * LL + (c - 256)];
  wT[idx] = f2bf(v);
}

// ============================================================================
// qkatt: fused per-node proj + attention + V projection (direct V stores).
//  P1: emb[n] f32 -> LDS bf16 [128][256] (row-swizzled)
//  P2 per half (rows 64h..64h+63):
//    a) V MFMA (accV[4] TRANSIENT) -> packed u32x2 stores to Vt global.
//       Layout Vt[n][col][rowpair]: u32 = bf16(row 2rp) | bf16(row 2rp+1)<<16.
//       Sub-line stores merge in write-back L2 -> no HBM amplification.
//       accV dead before Q|K MFMAs (round-4 register lifetime).
//    b) Q|K MFMA (acc[2][4]); sync; epilogue -> sE rows of this half; sync.
//  P3: S = Q K^T (MFMA), tanh, att -> d_out, colmean -> cOut.
// LDS 68 KB -> 2 blocks/CU (round 8's 80 KB fit only 1: occupancy 23%).
// ============================================================================
#define QA_LDS (65536 + 4096)
__global__ __launch_bounds__(512, 4)
void qkatt(const float* __restrict__ emb, const unsigned short* __restrict__ wT,
           const float* __restrict__ bq, const float* __restrict__ bk,
           float* __restrict__ attOut, float* __restrict__ cOut,
           unsigned* __restrict__ Vt)
{
  extern __shared__ char lds[];
  unsigned short* sE = (unsigned short*)lds;           // [128][256] bf16
  float* scr = (float*)(lds + 65536);                  // [8][128] colsums

  const int n    = blockIdx.x;
  const int tid  = threadIdx.x;
  const int wid  = tid >> 6;
  const int lane = tid & 63;
  const int lx   = lane & 15;
  const int g    = lane >> 4;
  const int sw   = (lx & 7) << 3;

  const float* embN = emb + (size_t)n * (SS * EMBD);

  // ---------------- P1: stage emb f32 -> bf16 LDS (swizzled) ----------------
  {
    const f32x4* src = (const f32x4*)embN;             // 8192 f32x4
    #pragma unroll
    for (int it = 0; it < 16; it++) {
      int i = it * 512 + tid;
      f32x4 v = src[i];
      int s = i >> 6, e0 = (i & 63) << 2;
      u16x4 h;
      h[0] = f2bf(v[0]); h[1] = f2bf(v[1]); h[2] = f2bf(v[2]); h[3] = f2bf(v[3]);
      *(u16x4*)(sE + s * 256 + (e0 ^ ((s & 7) << 3))) = h;
    }
  }
  __syncthreads();                                     // sync A

  const int col0 = (wid << 5) + lx;                    // Q|K col base (+n2*16)
  const int vcol = (wid << 4) + lx;                    // V col
  float bias[2];
  bias[0] = (col0      < 128) ? bq[col0]      : bk[col0 - 128];
  bias[1] = (col0 + 16 < 128) ? bq[col0 + 16] : bk[col0 + 16 - 128];

  // ---------------- P2: proj, two row-halves --------------------------------
  #pragma unroll 1
  for (int half = 0; half < 2; half++) {
    // --- (a) V projection: accV transient, direct packed global stores ---
    {
      f32x4 accV[4];
      #pragma unroll
      for (int m = 0; m < 4; m++) accV[m] = f32x4{0.f, 0.f, 0.f, 0.f};
      u32x4 B[8];
      const unsigned short* wp = wT + (size_t)(256 + vcol) * 256 + g * 8;
      #pragma unroll
      for (int ks = 0; ks < 8; ks++) B[ks] = *(const u32x4*)(wp + ks * 32);
      #pragma unroll
      for (int m = 0; m < 4; m++) {
        const unsigned short* ap = sE + (half * 64 + m * 16 + lx) * 256;
        #pragma unroll
        for (int ks = 0; ks < 8; ks++) {
          u32x4 A = *(const u32x4*)(ap + ((ks * 32 + g * 8) ^ sw));
          accV[m] = __builtin_amdgcn_mfma_f32_16x16x32_bf16(
                      __builtin_bit_cast(bf16x8, A), __builtin_bit_cast(bf16x8, B[ks]),
                      accV[m], 0, 0, 0);
        }
      }
      // rows half*64+m*16+g*4+{0..3} -> rowpairs rp = half*32+m*8+g*2 + {0,1}
      unsigned* vdst = Vt + (size_t)n * (128 * 64) + (size_t)vcol * 64
                     + half * 32 + g * 2;
      #pragma unroll
      for (int m = 0; m < 4; m++) {
        u32x2 pk;
        pk[0] = (unsigned)f2bf(accV[m][0]) | ((unsigned)f2bf(accV[m][1]) << 16);
        pk[1] = (unsigned)f2bf(accV[m][2]) | ((unsigned)f2bf(accV[m][3]) << 16);
        *(u32x2*)(vdst + m * 8) = pk;
      }
    }                                                  // accV dead here

    // --- (b) Q|K projection ---
    f32x4 acc[2][4];
    #pragma unroll
    for (int n2 = 0; n2 < 2; n2++)
      #pragma unroll
      for (int m = 0; m < 4; m++) acc[n2][m] = f32x4{0.f, 0.f, 0.f, 0.f};

    #pragma unroll
    for (int n2 = 0; n2 < 2; n2++) {
      u32x4 B[8];
      const unsigned short* wp = wT + (size_t)(col0 + n2 * 16) * 256 + g * 8;
      #pragma unroll
      for (int ks = 0; ks < 8; ks++) B[ks] = *(const u32x4*)(wp + ks * 32);
      #pragma unroll
      for (int m = 0; m < 4; m++) {
        const unsigned short* ap = sE + (half * 64 + m * 16 + lx) * 256;
        #pragma unroll
        for (int ks = 0; ks < 8; ks++) {
          u32x4 A = *(const u32x4*)(ap + ((ks * 32 + g * 8) ^ sw));
          acc[n2][m] = __builtin_amdgcn_mfma_f32_16x16x32_bf16(
                         __builtin_bit_cast(bf16x8, A), __builtin_bit_cast(bf16x8, B[ks]),
                         acc[n2][m], 0, 0, 0);
        }
      }
    }
    __syncthreads();                                   // B1: all sE reads of half done

    // epilogue: Q|K (+bias) -> bf16 -> rows [64*half, 64*half+64), swizzled
    #pragma unroll
    for (int n2 = 0; n2 < 2; n2++) {
      const int col = col0 + n2 * 16;
      const float bb = bias[n2];
      #pragma unroll
      for (int m = 0; m < 4; m++)
        #pragma unroll
        for (int r = 0; r < 4; r++) {
          const int srow = half * 64 + m * 16 + g * 4 + r;
          sE[srow * 256 + (col ^ ((srow & 7) << 3))] = f2bf(acc[n2][m][r] + bb);
        }
    }
    __syncthreads();                                   // B2: epilogue visible
  }

  // ---------------- P3: S = Q K^T, tanh, att store, colmean -----------------
  bf16x8 qf[4];
  #pragma unroll
  for (int ks = 0; ks < 4; ks++)
    qf[ks] = __builtin_bit_cast(bf16x8,
      *(const u32x4*)(sE + (wid * 16 + lx) * 256 + ((ks * 32 + g * 8) ^ sw)));

  f32x4 accS[8];
  #pragma unroll
  for (int nt = 0; nt < 8; nt++) accS[nt] = f32x4{0.f, 0.f, 0.f, 0.f};
  #pragma unroll
  for (int nt = 0; nt < 8; nt++) {
    const int tr = nt * 16 + lx;
    #pragma unroll
    for (int ks = 0; ks < 4; ks++) {
      u32x4 t = *(const u32x4*)(sE + tr * 256 + 128 + ((ks * 32 + g * 8) ^ sw));
      accS[nt] = __builtin_amdgcn_mfma_f32_16x16x32_bf16(
                   qf[ks], __builtin_bit_cast(bf16x8, t), accS[nt], 0, 0, 0);
    }
  }

  {
    float* slot = attOut + (size_t)n * (SS * SS);
    const int srow0 = wid * 16 + g * 4;
    float colp[8];
    #pragma unroll
    for (int nt = 0; nt < 8; nt++) {
      float p = 0.f;
      #pragma unroll
      for (int r = 0; r < 4; r++) {
        float x  = accS[nt][r] * 0.0625f;              // 1/sqrt(256)
        float ax = fabsf(x);
        float ex = __expf(ax * 2.0f);
        float th = __builtin_copysignf(__fdividef(ex - 1.0f, ex + 1.0f), x);
        p += th;
        slot[(size_t)(srow0 + r) * SS + nt * 16 + lx] = th;
      }
      p += __shfl_xor(p, 16, 64);
      p += __shfl_xor(p, 32, 64);                      // sum over strip's 16 rows
      colp[nt] = p;
    }
    if (lane < 16) {
      #pragma unroll
      for (int nt = 0; nt < 8; nt++) scr[wid * 128 + nt * 16 + lane] = colp[nt];
    }
  }
  __syncthreads();

  if (tid < 128) {
    float s = 0.f;
    #pragma unroll
    for (int w = 0; w < 8; w++) s += scr[w * 128 + tid];
    cOut[(size_t)n * 128 + tid] = s * (1.0f / 128.0f);
  }
}

// ============================================================================
// zkerV: z[n] = (c @ V + (sum c)*bv) @ Wo + bo
// Vt layout [N][128 col][64 rowpair-u32]; 32 KB slab staged to LDS coalesced,
// computed from padded [128][65] (pad kills the 64-stride bank conflict).
// ============================================================================
__global__ __launch_bounds__(256)
void zkerV(const unsigned* __restrict__ Vt, const float* __restrict__ cIn,
           const float* __restrict__ bv, const float* __restrict__ Wo,
           const float* __restrict__ bo, float* __restrict__ zOut)
{
  __shared__ unsigned sV[128 * 65];
  __shared__ float cS[128], mS[128], scr2[256], csS[2];
  const int n = blockIdx.x, tid = threadIdx.x;

  if (tid < 128) {
    float c = cIn[(size_t)n * 128 + tid];
    cS[tid] = c;
    float r = c;
    #pragma unroll
    for (int off = 32; off >= 1; off >>= 1) r += __shfl_down(r, off, 64);
    if ((tid & 63) == 0) csS[tid >> 6] = r;
  }

  // stage Vt slab (32 KB) coalesced -> sV [col][65]
  {
    const u32x4* src = (const u32x4*)(Vt + (size_t)n * (128 * 64));
    #pragma unroll
    for (int it = 0; it < 8; it++) {
      int i = it * 256 + tid;                          // 2048 u32x4
      u32x4 v = src[i];
      int col = i >> 4, rp0 = (i & 15) << 2;
      unsigned* d = sV + col * 65 + rp0;
      d[0] = v[0]; d[1] = v[1]; d[2] = v[2]; d[3] = v[3];
    }
  }
  __syncthreads();

  // m[l] = sum_t c[t] * V[t][l]  (2-way rowpair split)
  {
    const int l = tid & 127, h = tid >> 7;
    const unsigned* vp = sV + l * 65;
    float a = 0.f;
    #pragma unroll 8
    for (int rp = h * 32; rp < h * 32 + 32; rp++) {
      unsigned w = vp[rp];
      a += cS[2 * rp] * bfLo(w) + cS[2 * rp + 1] * bfHi(w);
    }
    scr2[tid] = a;
  }
  __syncthreads();
  if (tid < 128) {
    float csum = csS[0] + csS[1];
    mS[tid] = scr2[tid] + scr2[128 + tid] + csum * bv[tid];
  }
  __syncthreads();

  // z[j] = m @ Wo + bo   (2-way l-split)
  {
    const int j = tid & 127, h = tid >> 7;
    float a = 0.f;
    #pragma unroll 8
    for (int i = 0; i < 64; i++)
      a += mS[h * 64 + i] * Wo[(size_t)(h * 64 + i) * LL + j];
    scr2[tid] = a;
  }
  __syncthreads();
  if (tid < 128)
    zOut[(size_t)n * LL + tid] = scr2[tid] + scr2[128 + tid] + bo[tid];
}

// ============================================================================
// GCN in z-space (scatter 128-dim), then output GEMM to 2000-dim
// ============================================================================
__global__ void gcn_deg(const int* __restrict__ eidx, float* __restrict__ deg) {
  int e = blockIdx.x * 256 + threadIdx.x;
  if (e < EE) atomicAdd(&deg[eidx[EE + e]], 1.0f);
}

__global__ void gcn_dinv(const float* __restrict__ deg, float* __restrict__ dinv) {
  int i = blockIdx.x * 256 + threadIdx.x;
  if (i < NN) dinv[i] = rsqrtf(deg[i] + 1.0f);      // +1 self loop
}

__global__ void gcn_self(const float* __restrict__ dinv, const float* __restrict__ z,
                         float* __restrict__ agg) {
  size_t gidx = (size_t)blockIdx.x * 256 + threadIdx.x;
  int i = (int)(gidx >> 7);
  float di = dinv[i];
  agg[gidx] = di * di * z[gidx];
}

__global__ void gcn_scatter(const int* __restrict__ eidx, const float* __restrict__ dinv,
                            const float* __restrict__ z, float* __restrict__ agg) {
  int w    = (blockIdx.x * blockDim.x + threadIdx.x) >> 6;
  int lane = threadIdx.x & 63;
  int nw   = (gridDim.x * blockDim.x) >> 6;
  for (int e = w; e < EE; e += nw) {
    int s = eidx[e], d = eidx[EE + e];
    float nrm = dinv[s] * dinv[d];
    atomicAdd(&agg[(size_t)d * 128 + lane],      nrm * z[(size_t)s * 128 + lane]);
    atomicAdd(&agg[(size_t)d * 128 + 64 + lane], nrm * z[(size_t)s * 128 + 64 + lane]);
  }
}

__global__ __launch_bounds__(256)
void out_gemm(const float* __restrict__ agg, const float* __restrict__ Wg,
              const float* __restrict__ bg, float* __restrict__ outp) {
  __shared__ float sA[8 * 128];
  const int nb = blockIdx.x * 8;
  const int tid = threadIdx.x;
  {
    const float4* src = (const float4*)(agg + (size_t)nb * 128);
    ((float4*)sA)[tid] = src[tid];
  }
  __syncthreads();
  const int g0 = tid * 8;
  if (g0 < HV) {
    float acc[8][8];
    #pragma unroll
    for (int i = 0; i < 8; i++)
      #pragma unroll
      for (int j = 0; j < 8; j++) acc[i][j] = 0.0f;
    #pragma unroll 2
    for (int l = 0; l < 128; l++) {
      float4 wa = *(const float4*)(Wg + (size_t)l * HV + g0);
      float4 wb = *(const float4*)(Wg + (size_t)l * HV + g0 + 4);
      float w[8] = {wa.x, wa.y, wa.z, wa.w, wb.x, wb.y, wb.z, wb.w};
      #pragma unroll
      for (int i = 0; i < 8; i++) {
        float a = sA[i * 128 + l];
        #pragma unroll
        for (int j = 0; j < 8; j++) acc[i][j] += a * w[j];
      }
    }
    float b[8];
    #pragma unroll
    for (int j = 0; j < 8; j++) b[j] = bg[g0 + j];
    #pragma unroll
    for (int i = 0; i < 8; i++) {
      float4 oa = make_float4(acc[i][0] + b[0], acc[i][1] + b[1], acc[i][2] + b[2], acc[i][3] + b[3]);
      float4 ob = make_float4(acc[i][4] + b[4], acc[i][5] + b[5], acc[i][6] + b[6], acc[i][7] + b[7]);
      *(float4*)(outp + (size_t)(nb + i) * HV + g0)     = oa;
      *(float4*)(outp + (size_t)(nb + i) * HV + g0 + 4) = ob;
    }
  }
}

// ============================================================================
extern "C" void kernel_launch(void* const* d_in, const int* in_sizes, int n_in,
                              void* d_out, int out_size, void* d_ws, size_t ws_size,
                              hipStream_t stream) {
  const float* emb  = (const float*)d_in[0];
  const int*   eidx = (const int*)d_in[1];
  const float* Wq = (const float*)d_in[2];
  const float* bq = (const float*)d_in[3];
  const float* Wk = (const float*)d_in[4];
  const float* bk = (const float*)d_in[5];
  const float* Wv = (const float*)d_in[6];
  const float* bv = (const float*)d_in[7];
  const float* Wo = (const float*)d_in[8];
  const float* bo = (const float*)d_in[9];
  const float* Wg = (const float*)d_in[10];
  const float* bg = (const float*)d_in[11];

  float* out  = (float*)d_out;
  float* attO = out;                                   // [N,S,S]
  float* zO   = out + (size_t)NN * SS * SS;            // [N,L]
  float* oO   = zO + (size_t)NN * LL;                  // [N,HV]

  float* wsf  = (float*)d_ws;
  float* deg  = wsf;                                   // [N]
  float* dinv = wsf + NN;                              // [N]
  float* agg  = wsf + 2 * NN;                          // [N,128] (4 MB)
  unsigned short* wT = (unsigned short*)(wsf + 2 * NN + (size_t)NN * 128); // 192 KB
  float* cWS  = (float*)((char*)wT + 3 * LL * EMBD * sizeof(unsigned short)); // [N,128]
  unsigned* Vws = (unsigned*)(cWS + (size_t)NN * 128); // [N][128][64] u32 (256 MB)

  (void)in_sizes; (void)n_in; (void)out_size; (void)ws_size;

  hipFuncSetAttribute((const void*)qkatt,
                      hipFuncAttributeMaxDynamicSharedMemorySize, QA_LDS);

  hipMemsetAsync(deg, 0, NN * sizeof(float), stream);
  gcn_deg <<<EE / 256, 256, 0, stream>>>(eidx, deg);
  gcn_dinv<<<NN / 256, 256, 0, stream>>>(deg, dinv);
  prep_w  <<<(3 * LL * EMBD) / 256, 256, 0, stream>>>(Wq, Wk, Wv, wT);

  qkatt<<<NN, 512, QA_LDS, stream>>>(emb, wT, bq, bk, attO, cWS, Vws);
  zkerV<<<NN, 256, 0, stream>>>(Vws, cWS, bv, Wo, bo, zO);

  gcn_self   <<<NN * 128 / 256, 256, 0, stream>>>(dinv, zO, agg);
  gcn_scatter<<<2048, 256, 0, stream>>>(eidx, dinv, zO, agg);
  out_gemm   <<<NN / 8, 256, 0, stream>>>(agg, Wg, bg, oO);
}

// Round 10
// 857.641 us; speedup vs baseline: 1.5240x; 1.5240x over previous
//
#include <hip/hip_runtime.h>
#include <cstdint>
#include <cstddef>

// Problem constants (fixed by reference)
#define NN   8192
#define SS   128
#define EMBD 256
#define LL   128
#define HV   2000
#define EE   131072

typedef float  f32x4  __attribute__((ext_vector_type(4)));
typedef __bf16 bf16x8 __attribute__((ext_vector_type(8)));
typedef unsigned int   u32x4 __attribute__((ext_vector_type(4)));
typedef unsigned int   u32x2 __attribute__((ext_vector_type(2)));
typedef unsigned short u16x4 __attribute__((ext_vector_type(4)));

__device__ __forceinline__ unsigned short f2bf(float f) {
  unsigned u; __builtin_memcpy(&u, &f, 4);
  unsigned r = u + 0x7fffu + ((u >> 16) & 1u);   // RNE
  return (unsigned short)(r >> 16);
}
__device__ __forceinline__ float bfLo(unsigned w) {
  unsigned x = w << 16; float f; __builtin_memcpy(&f, &x, 4); return f;
}
__device__ __forceinline__ float bfHi(unsigned w) {
  unsigned x = w & 0xffff0000u; float f; __builtin_memcpy(&f, &x, 4); return f;
}

// ============================================================================
// prep: wT[col][e] bf16, col in [0,384):
//   col<128 -> Wq[:,col] ; col<256 -> Wk[:,col-128] ; else Wv[:,col-256]
// ============================================================================
__global__ void prep_w(const float* __restrict__ Wq, const float* __restrict__ Wk,
                       const float* __restrict__ Wv, unsigned short* __restrict__ wT) {
  int idx = blockIdx.x * 256 + threadIdx.x;      // 98304 = 384 cols x 256 e
  int c = idx >> 8, e = idx & 255;
  float v = (c < 128) ? Wq[(size_t)e * LL + c]
          : (c < 256) ? Wk[(size_t)e * LL + (c - 128)]
                      : Wv[(size_t)e * LL + (c - 256)];
  wT[idx] = f2bf(v);
}

// ============================================================================
// qkatt: fused per-node proj + attention + V projection (direct V stores).
// LAUNCH BOUNDS NOTE (rounds 5/6/8/9 forensic): with 512-thread blocks the
// 2nd arg is min waves/EU. (512,4) makes the allocator target the 64-VGPR
// tier -> spills ~56 regs -> +1.9 GB scratch traffic (rounds 5,6,9).
// (512,2) lands at ~120 VGPR spill-free (round 8). LDS (68 KB -> 2 blk/CU)
// and VGPR (120 -> 4 waves/EU) then both permit 16 waves/CU.
// ============================================================================
#define QA_LDS (65536 + 4096)
__global__ __launch_bounds__(512, 2)
void qkatt(const float* __restrict__ emb, const unsigned short* __restrict__ wT,
           const float* __restrict__ bq, const float* __restrict__ bk,
           float* __restrict__ attOut, float* __restrict__ cOut,
           unsigned* __restrict__ Vt)
{
  extern __shared__ char lds[];
  unsigned short* sE = (unsigned short*)lds;           // [128][256] bf16
  float* scr = (float*)(lds + 65536);                  // [8][128] colsums

  const int n    = blockIdx.x;
  const int tid  = threadIdx.x;
  const int wid  = tid >> 6;
  const int lane = tid & 63;
  const int lx   = lane & 15;
  const int g    = lane >> 4;
  const int sw   = (lx & 7) << 3;

  const float* embN = emb + (size_t)n * (SS * EMBD);

  // ---------------- P1: stage emb f32 -> bf16 LDS (swizzled) ----------------
  {
    const f32x4* src = (const f32x4*)embN;             // 8192 f32x4
    #pragma unroll
    for (int it = 0; it < 16; it++) {
      int i = it * 512 + tid;
      f32x4 v = src[i];
      int s = i >> 6, e0 = (i & 63) << 2;
      u16x4 h;
      h[0] = f2bf(v[0]); h[1] = f2bf(v[1]); h[2] = f2bf(v[2]); h[3] = f2bf(v[3]);
      *(u16x4*)(sE + s * 256 + (e0 ^ ((s & 7) << 3))) = h;
    }
  }
  __syncthreads();                                     // sync A

  const int col0 = (wid << 5) + lx;                    // Q|K col base (+n2*16)
  const int vcol = (wid << 4) + lx;                    // V col
  float bias[2];
  bias[0] = (col0      < 128) ? bq[col0]      : bk[col0 - 128];
  bias[1] = (col0 + 16 < 128) ? bq[col0 + 16] : bk[col0 + 16 - 128];

  // ---------------- P2: proj, two row-halves --------------------------------
  #pragma unroll 1
  for (int half = 0; half < 2; half++) {
    // --- (a) V projection: accV transient, direct packed global stores ---
    {
      f32x4 accV[4];
      #pragma unroll
      for (int m = 0; m < 4; m++) accV[m] = f32x4{0.f, 0.f, 0.f, 0.f};
      u32x4 B[8];
      const unsigned short* wp = wT + (size_t)(256 + vcol) * 256 + g * 8;
      #pragma unroll
      for (int ks = 0; ks < 8; ks++) B[ks] = *(const u32x4*)(wp + ks * 32);
      #pragma unroll
      for (int m = 0; m < 4; m++) {
        const unsigned short* ap = sE + (half * 64 + m * 16 + lx) * 256;
        #pragma unroll
        for (int ks = 0; ks < 8; ks++) {
          u32x4 A = *(const u32x4*)(ap + ((ks * 32 + g * 8) ^ sw));
          accV[m] = __builtin_amdgcn_mfma_f32_16x16x32_bf16(
                      __builtin_bit_cast(bf16x8, A), __builtin_bit_cast(bf16x8, B[ks]),
                      accV[m], 0, 0, 0);
        }
      }
      // rows half*64+m*16+g*4+{0..3} -> rowpairs rp = half*32+m*8+g*2 + {0,1}
      unsigned* vdst = Vt + (size_t)n * (128 * 64) + (size_t)vcol * 64
                     + half * 32 + g * 2;
      #pragma unroll
      for (int m = 0; m < 4; m++) {
        u32x2 pk;
        pk[0] = (unsigned)f2bf(accV[m][0]) | ((unsigned)f2bf(accV[m][1]) << 16);
        pk[1] = (unsigned)f2bf(accV[m][2]) | ((unsigned)f2bf(accV[m][3]) << 16);
        *(u32x2*)(vdst + m * 8) = pk;
      }
    }                                                  // accV dead here

    // --- (b) Q|K projection ---
    f32x4 acc[2][4];
    #pragma unroll
    for (int n2 = 0; n2 < 2; n2++)
      #pragma unroll
      for (int m = 0; m < 4; m++) acc[n2][m] = f32x4{0.f, 0.f, 0.f, 0.f};

    #pragma unroll
    for (int n2 = 0; n2 < 2; n2++) {
      u32x4 B[8];
      const unsigned short* wp = wT + (size_t)(col0 + n2 * 16) * 256 + g * 8;
      #pragma unroll
      for (int ks = 0; ks < 8; ks++) B[ks] = *(const u32x4*)(wp + ks * 32);
      #pragma unroll
      for (int m = 0; m < 4; m++) {
        const unsigned short* ap = sE + (half * 64 + m * 16 + lx) * 256;
        #pragma unroll
        for (int ks = 0; ks < 8; ks++) {
          u32x4 A = *(const u32x4*)(ap + ((ks * 32 + g * 8) ^ sw));
          acc[n2][m] = __builtin_amdgcn_mfma_f32_16x16x32_bf16(
                         __builtin_bit_cast(bf16x8, A), __builtin_bit_cast(bf16x8, B[ks]),
                         acc[n2][m], 0, 0, 0);
        }
      }
    }
    __syncthreads();                                   // B1: all sE reads of half done

    // epilogue: Q|K (+bias) -> bf16 -> rows [64*half, 64*half+64), swizzled
    #pragma unroll
    for (int n2 = 0; n2 < 2; n2++) {
      const int col = col0 + n2 * 16;
      const float bb = bias[n2];
      #pragma unroll
      for (int m = 0; m < 4; m++)
        #pragma unroll
        for (int r = 0; r < 4; r++) {
          const int srow = half * 64 + m * 16 + g * 4 + r;
          sE[srow * 256 + (col ^ ((srow & 7) << 3))] = f2bf(acc[n2][m][r] + bb);
        }
    }
    __syncthreads();                                   // B2: epilogue visible
  }

  // ---------------- P3: S = Q K^T, tanh, att store, colmean -----------------
  bf16x8 qf[4];
  #pragma unroll
  for (int ks = 0; ks < 4; ks++)
    qf[ks] = __builtin_bit_cast(bf16x8,
      *(const u32x4*)(sE + (wid * 16 + lx) * 256 + ((ks * 32 + g * 8) ^ sw)));

  f32x4 accS[8];
  #pragma unroll
  for (int nt = 0; nt < 8; nt++) accS[nt] = f32x4{0.f, 0.f, 0.f, 0.f};
  #pragma unroll
  for (int nt = 0; nt < 8; nt++) {
    const int tr = nt * 16 + lx;
    #pragma unroll
    for (int ks = 0; ks < 4; ks++) {
      u32x4 t = *(const u32x4*)(sE + tr * 256 + 128 + ((ks * 32 + g * 8) ^ sw));
      accS[nt] = __builtin_amdgcn_mfma_f32_16x16x32_bf16(
                   qf[ks], __builtin_bit_cast(bf16x8, t), accS[nt], 0, 0, 0);
    }
  }

  {
    float* slot = attOut + (size_t)n * (SS * SS);
    const int srow0 = wid * 16 + g * 4;
    float colp[8];
    #pragma unroll
    for (int nt = 0; nt < 8; nt++) {
      float p = 0.f;
      #pragma unroll
      for (int r = 0; r < 4; r++) {
        float x  = accS[nt][r] * 0.0625f;              // 1/sqrt(256)
        float ax = fabsf(x);
        float ex = __expf(ax * 2.0f);
        float th = __builtin_copysignf(__fdividef(ex - 1.0f, ex + 1.0f), x);
        p += th;
        slot[(size_t)(srow0 + r) * SS + nt * 16 + lx] = th;
      }
      p += __shfl_xor(p, 16, 64);
      p += __shfl_xor(p, 32, 64);                      // sum over strip's 16 rows
      colp[nt] = p;
    }
    if (lane < 16) {
      #pragma unroll
      for (int nt = 0; nt < 8; nt++) scr[wid * 128 + nt * 16 + lane] = colp[nt];
    }
  }
  __syncthreads();

  if (tid < 128) {
    float s = 0.f;
    #pragma unroll
    for (int w = 0; w < 8; w++) s += scr[w * 128 + tid];
    cOut[(size_t)n * 128 + tid] = s * (1.0f / 128.0f);
  }
}

// ============================================================================
// zkerV: z[n] = (c @ V + (sum c)*bv) @ Wo + bo
// Vt layout [N][128 col][64 rowpair-u32]; 32 KB slab staged to LDS coalesced,
// computed from padded [128][65] (pad kills the 64-stride bank conflict).
// ============================================================================
__global__ __launch_bounds__(256)
void zkerV(const unsigned* __restrict__ Vt, const float* __restrict__ cIn,
           const float* __restrict__ bv, const float* __restrict__ Wo,
           const float* __restrict__ bo, float* __restrict__ zOut)
{
  __shared__ unsigned sV[128 * 65];
  __shared__ float cS[128], mS[128], scr2[256], csS[2];
  const int n = blockIdx.x, tid = threadIdx.x;

  if (tid < 128) {
    float c = cIn[(size_t)n * 128 + tid];
    cS[tid] = c;
    float r = c;
    #pragma unroll
    for (int off = 32; off >= 1; off >>= 1) r += __shfl_down(r, off, 64);
    if ((tid & 63) == 0) csS[tid >> 6] = r;
  }

  // stage Vt slab (32 KB) coalesced -> sV [col][65]
  {
    const u32x4* src = (const u32x4*)(Vt + (size_t)n * (128 * 64));
    #pragma unroll
    for (int it = 0; it < 8; it++) {
      int i = it * 256 + tid;                          // 2048 u32x4
      u32x4 v = src[i];
      int col = i >> 4, rp0 = (i & 15) << 2;
      unsigned* d = sV + col * 65 + rp0;
      d[0] = v[0]; d[1] = v[1]; d[2] = v[2]; d[3] = v[3];
    }
  }
  __syncthreads();

  // m[l] = sum_t c[t] * V[t][l]  (2-way rowpair split)
  {
    const int l = tid & 127, h = tid >> 7;
    const unsigned* vp = sV + l * 65;
    float a = 0.f;
    #pragma unroll 8
    for (int rp = h * 32; rp < h * 32 + 32; rp++) {
      unsigned w = vp[rp];
      a += cS[2 * rp] * bfLo(w) + cS[2 * rp + 1] * bfHi(w);
    }
    scr2[tid] = a;
  }
  __syncthreads();
  if (tid < 128) {
    float csum = csS[0] + csS[1];
    mS[tid] = scr2[tid] + scr2[128 + tid] + csum * bv[tid];
  }
  __syncthreads();

  // z[j] = m @ Wo + bo   (2-way l-split)
  {
    const int j = tid & 127, h = tid >> 7;
    float a = 0.f;
    #pragma unroll 8
    for (int i = 0; i < 64; i++)
      a += mS[h * 64 + i] * Wo[(size_t)(h * 64 + i) * LL + j];
    scr2[tid] = a;
  }
  __syncthreads();
  if (tid < 128)
    zOut[(size_t)n * LL + tid] = scr2[tid] + scr2[128 + tid] + bo[tid];
}

// ============================================================================
// GCN in z-space (scatter 128-dim), then output GEMM to 2000-dim
// ============================================================================
__global__ void gcn_deg(const int* __restrict__ eidx, float* __restrict__ deg) {
  int e = blockIdx.x * 256 + threadIdx.x;
  if (e < EE) atomicAdd(&deg[eidx[EE + e]], 1.0f);
}

__global__ void gcn_dinv(const float* __restrict__ deg, float* __restrict__ dinv) {
  int i = blockIdx.x * 256 + threadIdx.x;
  if (i < NN) dinv[i] = rsqrtf(deg[i] + 1.0f);      // +1 self loop
}

__global__ void gcn_self(const float* __restrict__ dinv, const float* __restrict__ z,
                         float* __restrict__ agg) {
  size_t gidx = (size_t)blockIdx.x * 256 + threadIdx.x;
  int i = (int)(gidx >> 7);
  float di = dinv[i];
  agg[gidx] = di * di * z[gidx];
}

__global__ void gcn_scatter(const int* __restrict__ eidx, const float* __restrict__ dinv,
                            const float* __restrict__ z, float* __restrict__ agg) {
  int w    = (blockIdx.x * blockDim.x + threadIdx.x) >> 6;
  int lane = threadIdx.x & 63;
  int nw   = (gridDim.x * blockDim.x) >> 6;
  for (int e = w; e < EE; e += nw) {
    int s = eidx[e], d = eidx[EE + e];
    float nrm = dinv[s] * dinv[d];
    atomicAdd(&agg[(size_t)d * 128 + lane],      nrm * z[(size_t)s * 128 + lane]);
    atomicAdd(&agg[(size_t)d * 128 + 64 + lane], nrm * z[(size_t)s * 128 + 64 + lane]);
  }
}

__global__ __launch_bounds__(256)
void out_gemm(const float* __restrict__ agg, const float* __restrict__ Wg,
              const float* __restrict__ bg, float* __restrict__ outp) {
  __shared__ float sA[8 * 128];
  const int nb = blockIdx.x * 8;
  const int tid = threadIdx.x;
  {
    const float4* src = (const float4*)(agg + (size_t)nb * 128);
    ((float4*)sA)[tid] = src[tid];
  }
  __syncthreads();
  const int g0 = tid * 8;
  if (g0 < HV) {
    float acc[8][8];
    #pragma unroll
    for (int i = 0; i < 8; i++)
      #pragma unroll
      for (int j = 0; j < 8; j++) acc[i][j] = 0.0f;
    #pragma unroll 2
    for (int l = 0; l < 128; l++) {
      float4 wa = *(const float4*)(Wg + (size_t)l * HV + g0);
      float4 wb = *(const float4*)(Wg + (size_t)l * HV + g0 + 4);
      float w[8] = {wa.x, wa.y, wa.z, wa.w, wb.x, wb.y, wb.z, wb.w};
      #pragma unroll
      for (int i = 0; i < 8; i++) {
        float a = sA[i * 128 + l];
        #pragma unroll
        for (int j = 0; j < 8; j++) acc[i][j] += a * w[j];
      }
    }
    float b[8];
    #pragma unroll
    for (int j = 0; j < 8; j++) b[j] = bg[g0 + j];
    #pragma unroll
    for (int i = 0; i < 8; i++) {
      float4 oa = make_float4(acc[i][0] + b[0], acc[i][1] + b[1], acc[i][2] + b[2], acc[i][3] + b[3]);
      float4 ob = make_float4(acc[i][4] + b[4], acc[i][5] + b[5], acc[i][6] + b[6], acc[i][7] + b[7]);
      *(float4*)(outp + (size_t)(nb + i) * HV + g0)     = oa;
      *(float4*)(outp + (size_t)(nb + i) * HV + g0 + 4) = ob;
    }
  }
}

// ============================================================================
extern "C" void kernel_launch(void* const* d_in, const int* in_sizes, int n_in,
                              void* d_out, int out_size, void* d_ws, size_t ws_size,
                              hipStream_t stream) {
  const float* emb  = (const float*)d_in[0];
  const int*   eidx = (const int*)d_in[1];
  const float* Wq = (const float*)d_in[2];
  const float* bq = (const float*)d_in[3];
  const float* Wk = (const float*)d_in[4];
  const float* bk = (const float*)d_in[5];
  const float* Wv = (const float*)d_in[6];
  const float* bv = (const float*)d_in[7];
  const float* Wo = (const float*)d_in[8];
  const float* bo = (const float*)d_in[9];
  const float* Wg = (const float*)d_in[10];
  const float* bg = (const float*)d_in[11];

  float* out  = (float*)d_out;
  float* attO = out;                                   // [N,S,S]
  float* zO   = out + (size_t)NN * SS * SS;            // [N,L]
  float* oO   = zO + (size_t)NN * LL;                  // [N,HV]

  float* wsf  = (float*)d_ws;
  float* deg  = wsf;                                   // [N]
  float* dinv = wsf + NN;                              // [N]
  float* agg  = wsf + 2 * NN;                          // [N,128] (4 MB)
  unsigned short* wT = (unsigned short*)(wsf + 2 * NN + (size_t)NN * 128); // 192 KB
  float* cWS  = (float*)((char*)wT + 3 * LL * EMBD * sizeof(unsigned short)); // [N,128]
  unsigned* Vws = (unsigned*)(cWS + (size_t)NN * 128); // [N][128][64] u32 (256 MB)

  (void)in_sizes; (void)n_in; (void)out_size; (void)ws_size;

  hipFuncSetAttribute((const void*)qkatt,
                      hipFuncAttributeMaxDynamicSharedMemorySize, QA_LDS);

  hipMemsetAsync(deg, 0, NN * sizeof(float), stream);
  gcn_deg <<<EE / 256, 256, 0, stream>>>(eidx, deg);
  gcn_dinv<<<NN / 256, 256, 0, stream>>>(deg, dinv);
  prep_w  <<<(3 * LL * EMBD) / 256, 256, 0, stream>>>(Wq, Wk, Wv, wT);

  qkatt<<<NN, 512, QA_LDS, stream>>>(emb, wT, bq, bk, attO, cWS, Vws);
  zkerV<<<NN, 256, 0, stream>>>(Vws, cWS, bv, Wo, bo, zO);

  gcn_self   <<<NN * 128 / 256, 256, 0, stream>>>(dinv, zO, agg);
  gcn_scatter<<<2048, 256, 0, stream>>>(eidx, dinv, zO, agg);
  out_gemm   <<<NN / 8, 256, 0, stream>>>(agg, Wg, bg, oO);
}